// Round 12
// baseline (330.584 us; speedup 1.0000x reference)
//
#include <hip/hip_runtime.h>
#include <math.h>

#define NN 4096   // nodes
#define LOG2E 1.44269504088896340736f

using f32x4  = __attribute__((ext_vector_type(4))) float;
using bf16x4 = __attribute__((ext_vector_type(4))) __bf16;
using bf16x8 = __attribute__((ext_vector_type(8))) __bf16;

// exp2 in one v_exp_f32 (inputs are pre-scaled by log2e)
#if __has_builtin(__builtin_amdgcn_exp2f)
#define EXP2(x) __builtin_amdgcn_exp2f(x)
#else
#define EXP2(x) __expf((x) * 0.6931471805599453f)
#endif

// counted-vmcnt barrier (T4): keep next-tile DMA in flight across the barrier.
#define WAITVM4_BARRIER asm volatile("s_waitcnt vmcnt(4)\ns_barrier" ::: "memory")
#define WAITVM0_BARRIER asm volatile("s_waitcnt vmcnt(0)\ns_barrier" ::: "memory")

// ---------------- async global->LDS staging (16B, XOR-swizzled chunks) ----------------
// Row f of 64 bf16 = 8 chunks of 8; LDS slot s of row f holds global chunk s^(f&7).
template<int FH, int THREADS>
__device__ __forceinline__ void stage_tile(const __bf16* __restrict__ hgp,
                                           __bf16* dst, int tid) {
#pragma unroll
    for (int it = 0; it < FH * 64 / 8 / THREADS; it++) {
        int c = tid + it * THREADS;
        int f = c >> 3, sl = c & 7;
        int g = sl ^ (f & 7);
        __builtin_amdgcn_global_load_lds(
            (const __attribute__((address_space(1))) void*)(hgp + (size_t)f * NN + g * 8),
            (__attribute__((address_space(3))) void*)(dst + (size_t)c * 8), 16, 0, 0);
    }
}

__device__ __forceinline__ void stage_g(const __bf16* __restrict__ base, int ldk,
                                        __bf16* dst, int tid) {
#pragma unroll
    for (int it = 0; it < 2; it++) {
        int c = tid + it * 256;
        int f = c >> 3, sl = c & 7;
        int g = sl ^ (f & 7);
        __builtin_amdgcn_global_load_lds(
            (const __attribute__((address_space(1))) void*)(base + (size_t)f * ldk + g * 8),
            (__attribute__((address_space(3))) void*)(dst + (size_t)c * 8), 16, 0, 0);
    }
}

// ---------------- fused prep: memset + prepack + cast + pack_adj ----------------
// pack_adj needs MASSIVE wave parallelism (dependent load->ballot chain):
// 4096 blocks x 4 waves x 16 iters works; 512x4x128 died (R8).
__global__ void prep_kernel(const int* __restrict__ adj, unsigned long long* __restrict__ bits,
                            const float* __restrict__ W_h, const float* __restrict__ b_h,
                            const float* __restrict__ W_o,
                            __bf16* __restrict__ Bt1, float* __restrict__ biasp,
                            __bf16* __restrict__ Bt2,
                            const float* __restrict__ X, __bf16* __restrict__ Xb,
                            float* __restrict__ zeros) {
    const int b = blockIdx.x, t = threadIdx.x;
    if (b < 1024) {                               // prepack + zeroing
        int idx = b * 256 + t;                    // [0, 262144)
        {
            int n = idx >> 9, k = idx & 511;
            int h = n >> 7, f = n & 127;
            Bt1[idx] = (__bf16)W_h[(size_t)h * 512 * 128 + k * 128 + f];
        }
        if (idx < 64 * 512) {
            int n = idx >> 9, k = idx & 511;
            Bt2[idx] = (__bf16)W_o[k * 64 + n];
        }
        if (idx < 512) biasp[idx] = b_h[idx];
        if (idx < (10 * NN) / 4)                  // zero s1h/s2h/s1o/s2o (40960 f32)
            *(f32x4*)(zeros + (size_t)idx * 4) = (f32x4){0.f, 0.f, 0.f, 0.f};
    } else if (b < 3072) {                        // cast X -> bf16
        int i = (b - 1024) * 256 + t;             // [0, 524288) x4 floats
        f32x4 v = *(const f32x4*)(X + (size_t)i * 4);
        bf16x4 o;
#pragma unroll
        for (int q = 0; q < 4; q++) o[q] = (__bf16)v[q];
        *(bf16x4*)(Xb + (size_t)i * 4) = o;
    } else {                                      // pack_adj, grid-strided
        int wave = (b - 3072) * 4 + (t >> 6);     // [0, 16384)
        int lane = t & 63;
        int g0 = wave * 16;                       // 16 consecutive 64-col groups
        for (int it = 0; it < 16; it++) {
            int gw = g0 + it;
            int v = adj[(size_t)gw * 64 + lane];
            unsigned long long m = __ballot(v > 0);
            if (lane == 0) bits[gw] = m;
        }
    }
}

// ---------------- fused bf16 MFMA GEMM ----------------
// FUSEA=0 (layer 1): A staged via global_load_lds, triple-buffer + counted vmcnt.
// FUSEA=1 (layer 2): A = combine1 fused inline (N=64: A read exactly once).
//   Layer-1 attn produces 8 j-split partials (R11), so FUSEA sums 8 slices.
template<int FUSEA>
__global__ __launch_bounds__(256) void gemm_fused_kernel(
    const __bf16* __restrict__ A, const __bf16* __restrict__ Bt,
    const float* __restrict__ bias,
    const float* __restrict__ a1, const float* __restrict__ a2,
    __bf16* __restrict__ Ht, float* __restrict__ s1, float* __restrict__ s2,
    const __bf16* __restrict__ accp, const float* __restrict__ lgin,
    int M, int N, int K)
{
    constexpr int NB = FUSEA ? 2 : 3;
    constexpr int JS1 = 8;                        // layer-1 j-splits (R11)
    __shared__ __attribute__((aligned(16))) __bf16 As[NB][64 * 64];
    __shared__ __attribute__((aligned(16))) __bf16 Bs[NB][64 * 64];
    __shared__ float sinv[4][64];                 // FUSEA: 1/lsum per (head, row)
    const int tid = threadIdx.x, w = tid >> 6, l = tid & 63, o = l >> 4, rl = l & 15;
    const int bm = blockIdx.y * 64, bn = blockIdx.x * 64;
    f32x4 acc[4] = {};
    const int KB = K / 64;

    // FUSEA A-staging: load JS1 js-slices of accp1, combine, elu, bf16,
    // swizzled ds_write (same op order as the old combine1 -> same values).
    auto stageA_fused = [&](int kb, __bf16* dst) {
#pragma unroll
        for (int it = 0; it < 2; it++) {
            int c = tid + it * 256;
            int f = c >> 3, sl = c & 7;
            int row = bm + f;
            int col = kb * 64 + sl * 8;
            float inv = sinv[kb >> 1][f];
            float vs[8] = {0.f, 0.f, 0.f, 0.f, 0.f, 0.f, 0.f, 0.f};
#pragma unroll
            for (int js = 0; js < JS1; js++) {
                bf16x8 t = *(const bf16x8*)(accp + ((size_t)js * NN + row) * 512 + col);
#pragma unroll
                for (int q = 0; q < 8; q++) vs[q] += (float)t[q];
            }
            bf16x8 ob;
#pragma unroll
            for (int q = 0; q < 8; q++) {
                float x = vs[q] * inv;
                x = x > 0.f ? x : __expf(x) - 1.f;
                ob[q] = (__bf16)x;
            }
            *(bf16x8*)(dst + ((size_t)f * 8 + (sl ^ (f & 7))) * 8) = ob;
        }
    };

    if constexpr (FUSEA) {
        {   // per-block inv table: head = tid>>6, row = tid&63
            int h = tid >> 6, r = tid & 63;
            float ls = 0.f;
#pragma unroll
            for (int js = 0; js < JS1; js++)
                ls += lgin[((size_t)(h * JS1 + js)) * NN + bm + r];
            sinv[h][r] = ls > 0.f ? 1.f / ls : 0.f;
        }
        __syncthreads();                          // sinv visible
        stageA_fused(0, &As[0][0]);
        stage_g(Bt + (size_t)bn * K, K, &Bs[0][0], tid);
        for (int kb = 0; kb < KB; kb++) {
            int b = kb & 1;
            __syncthreads();                      // As[b]/Bs[b] ready
            if (kb + 1 < KB) {
                stageA_fused(kb + 1, &As[b ^ 1][0]);
                stage_g(Bt + (size_t)bn * K + (kb + 1) * 64, K, &Bs[b ^ 1][0], tid);
            }
#pragma unroll
            for (int kt = 0; kt < 2; kt++) {
                int ra = w * 16 + rl;
                int cg = kt * 4 + o;
                bf16x8 af = *(const bf16x8*)(&As[b][(ra * 8 + (cg ^ (ra & 7))) * 8]);
#pragma unroll
                for (int nt = 0; nt < 4; nt++) {
                    int rb = nt * 16 + rl;
                    bf16x8 bfr = *(const bf16x8*)(&Bs[b][(rb * 8 + (cg ^ (rb & 7))) * 8]);
                    acc[nt] = __builtin_amdgcn_mfma_f32_16x16x32_bf16(af, bfr, acc[nt], 0, 0, 0);
                }
            }
        }
    } else {
        // prologue: stage tiles 0 and 1 (8 DMA instructions in flight)
        stage_g(A + (size_t)bm * K, K, &As[0][0], tid);
        stage_g(Bt + (size_t)bn * K, K, &Bs[0][0], tid);
        stage_g(A + (size_t)bm * K + 64, K, &As[1][0], tid);
        stage_g(Bt + (size_t)bn * K + 64, K, &Bs[1][0], tid);
        int b = 0;
        for (int kb = 0; kb < KB; kb++) {
            if (kb + 1 < KB) { WAITVM4_BARRIER; } // tile kb landed; kb+1 in flight
            else             { WAITVM0_BARRIER; } // last tile: full drain
#pragma unroll
            for (int kt = 0; kt < 2; kt++) {
                int ra = w * 16 + rl;
                int cg = kt * 4 + o;
                bf16x8 af = *(const bf16x8*)(&As[b][(ra * 8 + (cg ^ (ra & 7))) * 8]);
#pragma unroll
                for (int nt = 0; nt < 4; nt++) {
                    int rb = nt * 16 + rl;
                    bf16x8 bfr = *(const bf16x8*)(&Bs[b][(rb * 8 + (cg ^ (rb & 7))) * 8]);
                    acc[nt] = __builtin_amdgcn_mfma_f32_16x16x32_bf16(af, bfr, acc[nt], 0, 0, 0);
                }
            }
            if (kb + 2 < KB) {                    // stage kb+2 (buffer free by now)
                int b2 = b + 2; if (b2 >= 3) b2 -= 3;
                stage_g(A + (size_t)bm * K + (kb + 2) * 64, K, &As[b2][0], tid);
                stage_g(Bt + (size_t)bn * K + (kb + 2) * 64, K, &Bs[b2][0], tid);
            }
            if (++b == 3) b = 0;
        }
    }
    // epilogue: bias, transposed bf16 store, s1/s2 row-dot partials
    const int head = bn >> 7;
    const int row_base = bm + w * 16 + o * 4;
    float p1[4] = {0.f, 0.f, 0.f, 0.f}, p2[4] = {0.f, 0.f, 0.f, 0.f};
#pragma unroll
    for (int nt = 0; nt < 4; nt++) {
        int col = bn + nt * 16 + rl;
        float bv = bias[col];
        float a1v = a1[col] * LOG2E, a2v = a2[col] * LOG2E;
        bf16x4 hv;
#pragma unroll
        for (int r4 = 0; r4 < 4; r4++) {
            float h = acc[nt][r4] + bv;
            hv[r4] = (__bf16)h;
            p1[r4] += h * a1v;
            p2[r4] += h * a2v;
        }
        *(bf16x4*)(Ht + (size_t)col * M + row_base) = hv;
    }
#pragma unroll
    for (int r4 = 0; r4 < 4; r4++)
#pragma unroll
        for (int off = 1; off < 16; off <<= 1) {
            p1[r4] += __shfl_xor(p1[r4], off, 64);
            p2[r4] += __shfl_xor(p2[r4], off, 64);
        }
    if (rl == 0)
#pragma unroll
        for (int r4 = 0; r4 < 4; r4++) {
            atomicAdd(&s1[(size_t)head * M + row_base + r4], p1[r4]);
            atomicAdd(&s2[(size_t)head * M + row_base + r4], p2[r4]);
        }
}

// ---------------- MFMA attention, SELF-CONSUME + E-factorized + NWAVES geometry ------
// R5 structure; R7 PMATH pipelining; R8 setprio placement; R10 E-factorization.
// R11/R12: NWAVES template — layer 1 uses 128-row / 8-wave / JSPLIT=8 blocks:
//  * 1024 blocks x 8 waves, LDS 36 KB -> 4 blocks/CU = 32 waves/CU (2x TLP;
//    the kernel has been slack-bound at 16 waves/CU since R5).
//  * hbuf j-tile is row-count independent -> 8 waves share each 16 KB DMA
//    (Htg L2 traffic halves).
//  * __launch_bounds__(512, 8) pins VGPR <= 64 (body compiles to exactly 64).
// Layer 2 keeps the proven 64-row / 4-wave / JSPLIT=16 config.
template<int FH, int JSPLIT, int NWAVES>
__global__ __launch_bounds__(NWAVES * 64, NWAVES) void attn_kernel(
    const __bf16* __restrict__ Htg,               // [heads*FH][NN]
    const unsigned long long* __restrict__ adj_bits,
    const float* __restrict__ s1_all, const float* __restrict__ s2_all,
    const float* __restrict__ ab_all,
    __bf16* __restrict__ accp,                    // [JSPLIT][NN][ldo]
    float* __restrict__ lg,                       // [heads*JSPLIT][NN]
    int ldo)
{
    constexpr int NJT = NN / 64 / JSPLIT;         // 8 (layer1) / 4 (layer2)
    constexpr int NTL = FH / 16;                  // n-tiles per wave (8 or 4)
    constexpr int THREADS = NWAVES * 64;
    const int head = blockIdx.y;
    const int js   = blockIdx.z;
    const int row0 = blockIdx.x * (NWAVES * 16);
    const int jt0  = js * NJT;
    const int tid = threadIdx.x;
    const int w = tid >> 6, l = tid & 63, o = l >> 4, rl = l & 15;
    const int myrow = row0 + w * 16 + rl;         // this wave's m-tile rows

    __shared__ __attribute__((aligned(16))) __bf16 hbuf[2][FH * 64];
    __shared__ __attribute__((aligned(16))) float el1[NJT * 64];
    __shared__ __attribute__((aligned(16))) float el2[NJT * 64];

    const float* s2 = s2_all + (size_t)head * NN;
    const __bf16* hg = Htg + (size_t)head * FH * NN;
    const float s1r = s1_all[(size_t)head * NN + myrow] + ab_all[head] * LOG2E;
    const float F1 = EXP2(s1r);                   // exp2 of row term
    const float F2 = EXP2(0.2f * s1r);            // exp2 of 0.2*row term
    float lacc = 0.f;                             // per-lane partial; reduced at end
    f32x4 acc[NTL] = {};                          // m-tile w, all n-tiles

    unsigned long long aw;                        // adjacency word (prefetched)
    auto PLOAD = [&](int jt) { aw = adj_bits[(size_t)myrow * 64 + jt]; };
    // PMATH reads E1/E2 from LDS at block-local tile index jl.
    auto PMATH = [&](int jl, bf16x8& f0, bf16x8& f1) {
        float ps = 0.f;
#pragma unroll
        for (int kt = 0; kt < 2; kt++) {
            unsigned int mb = (unsigned int)(aw >> ((kt * 4 + o) * 8)) & 0xFFu;
            int eb = jl * 64 + kt * 32 + o * 8;
            f32x4 e1a = *(const f32x4*)(&el1[eb]);
            f32x4 e1b = *(const f32x4*)(&el1[eb + 4]);
            f32x4 e2a = *(const f32x4*)(&el2[eb]);
            f32x4 e2b = *(const f32x4*)(&el2[eb + 4]);
#pragma unroll
            for (int q = 0; q < 8; q++) {
                float e1 = (q < 4) ? e1a[q] : e1b[q - 4];
                float e2 = (q < 4) ? e2a[q] : e2b[q - 4];
                float p = fmaxf(F1 * e1, F2 * e2);
                p = ((mb >> q) & 1u) ? p : 0.f;
                if (kt == 0) f0[q] = (__bf16)p; else f1[q] = (__bf16)p;
                ps += p;
            }
        }
        lacc += ps;
    };

    stage_tile<FH, THREADS>(hg + (size_t)jt0 * 64, &hbuf[0][0], tid);
    // one-time E table for this block's j range (coalesced s2 reads)
    for (int i = tid; i < NJT * 64; i += THREADS) {
        float s = s2[jt0 * 64 + i];
        el1[i] = EXP2(s);
        el2[i] = EXP2(0.2f * s);
    }
    PLOAD(jt0);
    __syncthreads();                              // el visible (also drains DMA 0)
    bf16x8 fc0, fc1, fn0, fn1;
    PMATH(0, fc0, fc1);                           // tile 0 fragments
    if (NJT > 1) PLOAD(jt0 + 1);

    for (int jl = 0; jl < NJT; jl++) {
        const int b = jl & 1;
        const int jt = jt0 + jl;
        // hbuf[b] DMA drained (vmcnt 0); hbuf[b^1] free to overwrite
        __syncthreads();
        if (jl + 1 < NJT)
            stage_tile<FH, THREADS>(hg + (size_t)(jt + 1) * 64, &hbuf[b ^ 1][0], tid);
        // produce NEXT tile's fragments — interleaves with the MFMA cluster
        if (jl + 1 < NJT) PMATH(jl + 1, fn0, fn1);
        if (jl + 2 < NJT) PLOAD(jt + 2);
        // consume: own m-tile, ALL n-tiles (wave-local, no cross-wave sync)
        __builtin_amdgcn_s_setprio(1);
#pragma unroll
        for (int ntl = 0; ntl < NTL; ntl++) {
            int f = ntl * 16 + rl;
            int s0 = o ^ (rl & 7);                // kt=0 slot
            int s1 = (4 + o) ^ (rl & 7);          // kt=1 slot
            bf16x8 b0 = *(const bf16x8*)(&hbuf[b][(f * 8 + s0) * 8]);
            bf16x8 b1 = *(const bf16x8*)(&hbuf[b][(f * 8 + s1) * 8]);
            acc[ntl] = __builtin_amdgcn_mfma_f32_16x16x32_bf16(fc0, b0, acc[ntl], 0, 0, 0);
            acc[ntl] = __builtin_amdgcn_mfma_f32_16x16x32_bf16(fc1, b1, acc[ntl], 0, 0, 0);
        }
        __builtin_amdgcn_s_setprio(0);
        if (jl + 1 < NJT) { fc0 = fn0; fc1 = fn1; }
    }
    // ---- epilogue: cross-lane lacc reduce (deferred from loop) ----
    lacc += __shfl_xor(lacc, 16, 64);
    lacc += __shfl_xor(lacc, 32, 64);
    if (l < 16) lg[((size_t)head * JSPLIT + js) * NN + row0 + w * 16 + l] = lacc;
#pragma unroll
    for (int ntl = 0; ntl < NTL; ntl++)
#pragma unroll
        for (int r4 = 0; r4 < 4; r4++) {
            int grow = row0 + w * 16 + o * 4 + r4;
            int gcol = head * FH + ntl * 16 + rl;
            accp[((size_t)js * NN + grow) * ldo + gcol] = (__bf16)acc[ntl][r4];
        }
}

// ---------------- combine layer-2 partials + elu + log_softmax -> out ----------------
__global__ void combine2_kernel(const __bf16* __restrict__ accp, const float* __restrict__ lg,
                                float* __restrict__ out) {
    int row = (blockIdx.x * 256 + threadIdx.x) >> 6;
    int lane = threadIdx.x & 63;
    if (row >= NN) return;
    float lsum = 0.f, v = 0.f;
#pragma unroll
    for (int js = 0; js < 16; js++) {
        lsum += lg[(size_t)js * NN + row];
        v += (float)accp[((size_t)js * NN + row) * 64 + lane];
    }
    float inv = lsum > 0.f ? 1.f / lsum : 0.f;
    v *= inv;
    v = v > 0.f ? v : __expf(v) - 1.f;
    float m = v;
#pragma unroll
    for (int off = 1; off < 64; off <<= 1) m = fmaxf(m, __shfl_xor(m, off, 64));
    float ex = __expf(v - m);
    float s = ex;
#pragma unroll
    for (int off = 1; off < 64; off <<= 1) s += __shfl_xor(s, off, 64);
    out[(size_t)row * 64 + lane] = v - m - __logf(s);
}

extern "C" void kernel_launch(void* const* d_in, const int* in_sizes, int n_in,
                              void* d_out, int out_size, void* d_ws, size_t ws_size,
                              hipStream_t stream) {
    const float* X    = (const float*)d_in[0];
    const int*   adj  = (const int*)d_in[1];
    const float* W_h  = (const float*)d_in[2];
    const float* b_h  = (const float*)d_in[3];
    const float* a1_h = (const float*)d_in[4];
    const float* a2_h = (const float*)d_in[5];
    const float* ab_h = (const float*)d_in[6];
    const float* W_o  = (const float*)d_in[7];
    const float* b_o  = (const float*)d_in[8];
    const float* a1_o = (const float*)d_in[9];
    const float* a2_o = (const float*)d_in[10];
    const float* ab_o = (const float*)d_in[11];
    float* out = (float*)d_out;

    // ---- workspace plan with LIFETIME OVERLAYS (R12) ----
    // R11 grew accp1 to 32 MB and blew the linear footprint from the proven
    // 41.65 MB (R0-R10) to ~52 MB -> suspected ws overflow = container crash.
    // Overlay rules (producer->consumer intervals, no temporal overlap):
    //   * Xb   [prep -> gemm1]   shares its base with accp1 [attn1 -> gemm2]
    //   * accp2 [attn2 -> combine2] aliases accp1's first 8 MB (dead after gemm2)
    //   * lg2   [attn2 -> combine2] aliases accp1+8 MB
    // Htg/Bt1 live BEFORE the overlay so attn1's Htg reads never collide with
    // its accp1 writes. Footprint: 8.1 MB front + 32 MB overlay = 41.65 MB.
    char* ws = (char*)d_ws;
    auto alloc = [&](size_t bytes) {
        char* p = ws; ws += (bytes + 255) & ~(size_t)255; return p;
    };
    unsigned long long* adj_bits = (unsigned long long*)alloc((size_t)NN * 64 * 8); // 2 MB
    __bf16* Bt2    = (__bf16*)alloc((size_t)64 * 512 * 2);      // 64 KB  [prep->gemm2]
    float*  s1h    = (float*)alloc((size_t)4 * NN * 4);         // |-- contiguous,
    float*  s2h    = (float*)alloc((size_t)4 * NN * 4);         // |   zeroed by prep
    float*  s1o    = (float*)alloc((size_t)NN * 4);             // |   (160 KB)
    float*  s2o    = (float*)alloc((size_t)NN * 4);             // |
    float*  lg1    = (float*)alloc((size_t)32 * NN * 4);        // 512 KB [attn1->gemm2]
    __bf16* Ht2    = (__bf16*)alloc((size_t)64 * NN * 2);       // 512 KB [gemm2->attn2]
    float*  biasp  = (float*)alloc(512 * 4);                    // 2 KB
    __bf16* Htg    = (__bf16*)alloc((size_t)512 * NN * 2);      // 4 MB  [gemm1->attn1]
    __bf16* Bt1    = (__bf16*)alloc((size_t)512 * 512 * 2);     // 512 KB [prep->gemm1]
    // ---- overlay region: 32 MB ----
    char*   ovl    = alloc((size_t)8 * NN * 512 * 2);           // 32 MB
    __bf16* Xb     = (__bf16*)ovl;                              // 4 MB  [prep->gemm1]
    __bf16* accp1  = (__bf16*)ovl;                              // 32 MB [attn1->gemm2]
    __bf16* accp2  = (__bf16*)ovl;                              // 8 MB  [attn2->combine2]
    float*  lg2    = (float*)(ovl + (size_t)16 * NN * 64 * 2);  // 256 KB @ +8 MB

    // 1. fused prep: adj->bits, weight prepack, X cast, s1/s2 zeroing
    prep_kernel<<<7168, 256, 0, stream>>>(adj, adj_bits, W_h, b_h, W_o,
                                          Bt1, biasp, Bt2, X, Xb, s1h);
    // 2. layer-1 GEMM fused: Htg (transposed bf16) + s1h/s2h atomics (LOG2E-scaled)
    gemm_fused_kernel<0><<<dim3(8, 64), 256, 0, stream>>>(
        Xb, Bt1, biasp, a1_h, a2_h, Htg, s1h, s2h, nullptr, nullptr, NN, 512, 512);
    // 3. attention layer 1 partials: 128-row/8-wave blocks, 8 j-splits
    //    (32 x 4 x 8 = 1024 blocks x 8 waves; 36 KB LDS -> 32 waves/CU)
    attn_kernel<128, 8, 8><<<dim3(NN / 128, 4, 8), 512, 0, stream>>>(
        Htg, adj_bits, s1h, s2h, ab_h, accp1, lg1, 512);
    // 4. layer-2 GEMM with combine1 FUSED into the A-path (sums 8 js slices)
    gemm_fused_kernel<1><<<dim3(1, 64), 256, 0, stream>>>(
        nullptr, Bt2, b_o, a1_o, a2_o, Ht2, s1o, s2o, accp1, lg1, NN, 64, 512);
    // 5. attention layer 2 partials (64-row/4-wave, 16 j-splits — unchanged)
    attn_kernel<64, 16, 4><<<dim3(NN / 64, 1, 16), 256, 0, stream>>>(
        Ht2, adj_bits, s1o, s2o, ab_o, accp2, lg2, 64);
    // 6. combine + elu + log_softmax -> out
    combine2_kernel<<<(NN * 64) / 256, 256, 0, stream>>>(accp2, lg2, out);
}

// Round 13
// 207.408 us; speedup vs baseline: 1.5939x; 1.5939x over previous
//
#include <hip/hip_runtime.h>
#include <math.h>

#define NN 4096   // nodes
#define LOG2E 1.44269504088896340736f

using f32x4  = __attribute__((ext_vector_type(4))) float;
using bf16x4 = __attribute__((ext_vector_type(4))) __bf16;
using bf16x8 = __attribute__((ext_vector_type(8))) __bf16;

// exp2 in one v_exp_f32 (inputs are pre-scaled by log2e)
#if __has_builtin(__builtin_amdgcn_exp2f)
#define EXP2(x) __builtin_amdgcn_exp2f(x)
#else
#define EXP2(x) __expf((x) * 0.6931471805599453f)
#endif

// counted-vmcnt barrier (T4): keep next-tile DMA in flight across the barrier.
#define WAITVM4_BARRIER asm volatile("s_waitcnt vmcnt(4)\ns_barrier" ::: "memory")
#define WAITVM0_BARRIER asm volatile("s_waitcnt vmcnt(0)\ns_barrier" ::: "memory")

// ---------------- async global->LDS staging (16B, XOR-swizzled chunks) ----------------
// Row f of 64 bf16 = 8 chunks of 8; LDS slot s of row f holds global chunk s^(f&7).
template<int FH, int THREADS>
__device__ __forceinline__ void stage_tile(const __bf16* __restrict__ hgp,
                                           __bf16* dst, int tid) {
#pragma unroll
    for (int it = 0; it < FH * 64 / 8 / THREADS; it++) {
        int c = tid + it * THREADS;
        int f = c >> 3, sl = c & 7;
        int g = sl ^ (f & 7);
        __builtin_amdgcn_global_load_lds(
            (const __attribute__((address_space(1))) void*)(hgp + (size_t)f * NN + g * 8),
            (__attribute__((address_space(3))) void*)(dst + (size_t)c * 8), 16, 0, 0);
    }
}

__device__ __forceinline__ void stage_g(const __bf16* __restrict__ base, int ldk,
                                        __bf16* dst, int tid) {
#pragma unroll
    for (int it = 0; it < 2; it++) {
        int c = tid + it * 256;
        int f = c >> 3, sl = c & 7;
        int g = sl ^ (f & 7);
        __builtin_amdgcn_global_load_lds(
            (const __attribute__((address_space(1))) void*)(base + (size_t)f * ldk + g * 8),
            (__attribute__((address_space(3))) void*)(dst + (size_t)c * 8), 16, 0, 0);
    }
}

// ---------------- fused prep: memset + prepack + cast + pack_adj ----------------
// pack_adj needs MASSIVE wave parallelism (dependent load->ballot chain):
// 4096 blocks x 4 waves x 16 iters works; 512x4x128 died (R8).
__global__ void prep_kernel(const int* __restrict__ adj, unsigned long long* __restrict__ bits,
                            const float* __restrict__ W_h, const float* __restrict__ b_h,
                            const float* __restrict__ W_o,
                            __bf16* __restrict__ Bt1, float* __restrict__ biasp,
                            __bf16* __restrict__ Bt2,
                            const float* __restrict__ X, __bf16* __restrict__ Xb,
                            float* __restrict__ zeros) {
    const int b = blockIdx.x, t = threadIdx.x;
    if (b < 1024) {                               // prepack + zeroing
        int idx = b * 256 + t;                    // [0, 262144)
        {
            int n = idx >> 9, k = idx & 511;
            int h = n >> 7, f = n & 127;
            Bt1[idx] = (__bf16)W_h[(size_t)h * 512 * 128 + k * 128 + f];
        }
        if (idx < 64 * 512) {
            int n = idx >> 9, k = idx & 511;
            Bt2[idx] = (__bf16)W_o[k * 64 + n];
        }
        if (idx < 512) biasp[idx] = b_h[idx];
        if (idx < (10 * NN) / 4)                  // zero s1h/s2h/s1o/s2o (40960 f32)
            *(f32x4*)(zeros + (size_t)idx * 4) = (f32x4){0.f, 0.f, 0.f, 0.f};
    } else if (b < 3072) {                        // cast X -> bf16
        int i = (b - 1024) * 256 + t;             // [0, 524288) x4 floats
        f32x4 v = *(const f32x4*)(X + (size_t)i * 4);
        bf16x4 o;
#pragma unroll
        for (int q = 0; q < 4; q++) o[q] = (__bf16)v[q];
        *(bf16x4*)(Xb + (size_t)i * 4) = o;
    } else {                                      // pack_adj, grid-strided
        int wave = (b - 3072) * 4 + (t >> 6);     // [0, 16384)
        int lane = t & 63;
        int g0 = wave * 16;                       // 16 consecutive 64-col groups
        for (int it = 0; it < 16; it++) {
            int gw = g0 + it;
            int v = adj[(size_t)gw * 64 + lane];
            unsigned long long m = __ballot(v > 0);
            if (lane == 0) bits[gw] = m;
        }
    }
}

// ---------------- fused bf16 MFMA GEMM ----------------
// FUSEA=0 (layer 1): A staged via global_load_lds, triple-buffer + counted vmcnt.
// FUSEA=1 (layer 2): A = combine1 fused inline (N=64: A read exactly once).
//   Layer-1 attn produces 8 j-split partials (R11), so FUSEA sums 8 slices.
template<int FUSEA>
__global__ __launch_bounds__(256) void gemm_fused_kernel(
    const __bf16* __restrict__ A, const __bf16* __restrict__ Bt,
    const float* __restrict__ bias,
    const float* __restrict__ a1, const float* __restrict__ a2,
    __bf16* __restrict__ Ht, float* __restrict__ s1, float* __restrict__ s2,
    const __bf16* __restrict__ accp, const float* __restrict__ lgin,
    int M, int N, int K)
{
    constexpr int NB = FUSEA ? 2 : 3;
    constexpr int JS1 = 8;                        // layer-1 j-splits (R11)
    __shared__ __attribute__((aligned(16))) __bf16 As[NB][64 * 64];
    __shared__ __attribute__((aligned(16))) __bf16 Bs[NB][64 * 64];
    __shared__ float sinv[4][64];                 // FUSEA: 1/lsum per (head, row)
    const int tid = threadIdx.x, w = tid >> 6, l = tid & 63, o = l >> 4, rl = l & 15;
    const int bm = blockIdx.y * 64, bn = blockIdx.x * 64;
    f32x4 acc[4] = {};
    const int KB = K / 64;

    // FUSEA A-staging: load JS1 js-slices of accp1, combine, elu, bf16,
    // swizzled ds_write (same op order as the old combine1 -> same values).
    auto stageA_fused = [&](int kb, __bf16* dst) {
#pragma unroll
        for (int it = 0; it < 2; it++) {
            int c = tid + it * 256;
            int f = c >> 3, sl = c & 7;
            int row = bm + f;
            int col = kb * 64 + sl * 8;
            float inv = sinv[kb >> 1][f];
            float vs[8] = {0.f, 0.f, 0.f, 0.f, 0.f, 0.f, 0.f, 0.f};
#pragma unroll
            for (int js = 0; js < JS1; js++) {
                bf16x8 t = *(const bf16x8*)(accp + ((size_t)js * NN + row) * 512 + col);
#pragma unroll
                for (int q = 0; q < 8; q++) vs[q] += (float)t[q];
            }
            bf16x8 ob;
#pragma unroll
            for (int q = 0; q < 8; q++) {
                float x = vs[q] * inv;
                x = x > 0.f ? x : __expf(x) - 1.f;
                ob[q] = (__bf16)x;
            }
            *(bf16x8*)(dst + ((size_t)f * 8 + (sl ^ (f & 7))) * 8) = ob;
        }
    };

    if constexpr (FUSEA) {
        {   // per-block inv table: head = tid>>6, row = tid&63
            int h = tid >> 6, r = tid & 63;
            float ls = 0.f;
#pragma unroll
            for (int js = 0; js < JS1; js++)
                ls += lgin[((size_t)(h * JS1 + js)) * NN + bm + r];
            sinv[h][r] = ls > 0.f ? 1.f / ls : 0.f;
        }
        __syncthreads();                          // sinv visible
        stageA_fused(0, &As[0][0]);
        stage_g(Bt + (size_t)bn * K, K, &Bs[0][0], tid);
        for (int kb = 0; kb < KB; kb++) {
            int b = kb & 1;
            __syncthreads();                      // As[b]/Bs[b] ready
            if (kb + 1 < KB) {
                stageA_fused(kb + 1, &As[b ^ 1][0]);
                stage_g(Bt + (size_t)bn * K + (kb + 1) * 64, K, &Bs[b ^ 1][0], tid);
            }
#pragma unroll
            for (int kt = 0; kt < 2; kt++) {
                int ra = w * 16 + rl;
                int cg = kt * 4 + o;
                bf16x8 af = *(const bf16x8*)(&As[b][(ra * 8 + (cg ^ (ra & 7))) * 8]);
#pragma unroll
                for (int nt = 0; nt < 4; nt++) {
                    int rb = nt * 16 + rl;
                    bf16x8 bfr = *(const bf16x8*)(&Bs[b][(rb * 8 + (cg ^ (rb & 7))) * 8]);
                    acc[nt] = __builtin_amdgcn_mfma_f32_16x16x32_bf16(af, bfr, acc[nt], 0, 0, 0);
                }
            }
        }
    } else {
        // prologue: stage tiles 0 and 1 (8 DMA instructions in flight)
        stage_g(A + (size_t)bm * K, K, &As[0][0], tid);
        stage_g(Bt + (size_t)bn * K, K, &Bs[0][0], tid);
        stage_g(A + (size_t)bm * K + 64, K, &As[1][0], tid);
        stage_g(Bt + (size_t)bn * K + 64, K, &Bs[1][0], tid);
        int b = 0;
        for (int kb = 0; kb < KB; kb++) {
            if (kb + 1 < KB) { WAITVM4_BARRIER; } // tile kb landed; kb+1 in flight
            else             { WAITVM0_BARRIER; } // last tile: full drain
#pragma unroll
            for (int kt = 0; kt < 2; kt++) {
                int ra = w * 16 + rl;
                int cg = kt * 4 + o;
                bf16x8 af = *(const bf16x8*)(&As[b][(ra * 8 + (cg ^ (ra & 7))) * 8]);
#pragma unroll
                for (int nt = 0; nt < 4; nt++) {
                    int rb = nt * 16 + rl;
                    bf16x8 bfr = *(const bf16x8*)(&Bs[b][(rb * 8 + (cg ^ (rb & 7))) * 8]);
                    acc[nt] = __builtin_amdgcn_mfma_f32_16x16x32_bf16(af, bfr, acc[nt], 0, 0, 0);
                }
            }
            if (kb + 2 < KB) {                    // stage kb+2 (buffer free by now)
                int b2 = b + 2; if (b2 >= 3) b2 -= 3;
                stage_g(A + (size_t)bm * K + (kb + 2) * 64, K, &As[b2][0], tid);
                stage_g(Bt + (size_t)bn * K + (kb + 2) * 64, K, &Bs[b2][0], tid);
            }
            if (++b == 3) b = 0;
        }
    }
    // epilogue: bias, transposed bf16 store, s1/s2 row-dot partials
    const int head = bn >> 7;
    const int row_base = bm + w * 16 + o * 4;
    float p1[4] = {0.f, 0.f, 0.f, 0.f}, p2[4] = {0.f, 0.f, 0.f, 0.f};
#pragma unroll
    for (int nt = 0; nt < 4; nt++) {
        int col = bn + nt * 16 + rl;
        float bv = bias[col];
        float a1v = a1[col] * LOG2E, a2v = a2[col] * LOG2E;
        bf16x4 hv;
#pragma unroll
        for (int r4 = 0; r4 < 4; r4++) {
            float h = acc[nt][r4] + bv;
            hv[r4] = (__bf16)h;
            p1[r4] += h * a1v;
            p2[r4] += h * a2v;
        }
        *(bf16x4*)(Ht + (size_t)col * M + row_base) = hv;
    }
#pragma unroll
    for (int r4 = 0; r4 < 4; r4++)
#pragma unroll
        for (int off = 1; off < 16; off <<= 1) {
            p1[r4] += __shfl_xor(p1[r4], off, 64);
            p2[r4] += __shfl_xor(p2[r4], off, 64);
        }
    if (rl == 0)
#pragma unroll
        for (int r4 = 0; r4 < 4; r4++) {
            atomicAdd(&s1[(size_t)head * M + row_base + r4], p1[r4]);
            atomicAdd(&s2[(size_t)head * M + row_base + r4], p2[r4]);
        }
}

// ---------------- MFMA attention, SELF-CONSUME + E-factorized + NWAVES geometry ------
// R5 structure; R7 PMATH pipelining; R8 setprio placement; R10 E-factorization.
// R11-R13: layer 1 uses 128-row / 8-wave / JSPLIT=8 blocks (1024 x 8 waves,
// 36 KB LDS -> 4 blocks/CU = 32 waves/CU, 2x TLP; hbuf shared by 8 waves
// halves Htg L2 traffic). Layer 2 keeps 64-row / 4-wave / JSPLIT=16.
// R13 FIX: __launch_bounds__ 2nd arg is empirically MIN BLOCKS PER CU on this
// toolchain (R12: (512,8) -> 8 blk x 8 waves = 16 waves/SIMD -> VGPR cap
// 512/16 = 32 -> catastrophic spill, 398 MB scratch writes). (NWAVES*64, 4)
// gives 4 blocks/CU: layer1 cap = 512/8 = 64 VGPR (body needs exactly 64),
// layer2 cap = 128 (body uses 64). No spill.
template<int FH, int JSPLIT, int NWAVES>
__global__ __launch_bounds__(NWAVES * 64, 4) void attn_kernel(
    const __bf16* __restrict__ Htg,               // [heads*FH][NN]
    const unsigned long long* __restrict__ adj_bits,
    const float* __restrict__ s1_all, const float* __restrict__ s2_all,
    const float* __restrict__ ab_all,
    __bf16* __restrict__ accp,                    // [JSPLIT][NN][ldo]
    float* __restrict__ lg,                       // [heads*JSPLIT][NN]
    int ldo)
{
    constexpr int NJT = NN / 64 / JSPLIT;         // 8 (layer1) / 4 (layer2)
    constexpr int NTL = FH / 16;                  // n-tiles per wave (8 or 4)
    constexpr int THREADS = NWAVES * 64;
    const int head = blockIdx.y;
    const int js   = blockIdx.z;
    const int row0 = blockIdx.x * (NWAVES * 16);
    const int jt0  = js * NJT;
    const int tid = threadIdx.x;
    const int w = tid >> 6, l = tid & 63, o = l >> 4, rl = l & 15;
    const int myrow = row0 + w * 16 + rl;         // this wave's m-tile rows

    __shared__ __attribute__((aligned(16))) __bf16 hbuf[2][FH * 64];
    __shared__ __attribute__((aligned(16))) float el1[NJT * 64];
    __shared__ __attribute__((aligned(16))) float el2[NJT * 64];

    const float* s2 = s2_all + (size_t)head * NN;
    const __bf16* hg = Htg + (size_t)head * FH * NN;
    const float s1r = s1_all[(size_t)head * NN + myrow] + ab_all[head] * LOG2E;
    const float F1 = EXP2(s1r);                   // exp2 of row term
    const float F2 = EXP2(0.2f * s1r);            // exp2 of 0.2*row term
    float lacc = 0.f;                             // per-lane partial; reduced at end
    f32x4 acc[NTL] = {};                          // m-tile w, all n-tiles

    unsigned long long aw;                        // adjacency word (prefetched)
    auto PLOAD = [&](int jt) { aw = adj_bits[(size_t)myrow * 64 + jt]; };
    // PMATH reads E1/E2 from LDS at block-local tile index jl.
    auto PMATH = [&](int jl, bf16x8& f0, bf16x8& f1) {
        float ps = 0.f;
#pragma unroll
        for (int kt = 0; kt < 2; kt++) {
            unsigned int mb = (unsigned int)(aw >> ((kt * 4 + o) * 8)) & 0xFFu;
            int eb = jl * 64 + kt * 32 + o * 8;
            f32x4 e1a = *(const f32x4*)(&el1[eb]);
            f32x4 e1b = *(const f32x4*)(&el1[eb + 4]);
            f32x4 e2a = *(const f32x4*)(&el2[eb]);
            f32x4 e2b = *(const f32x4*)(&el2[eb + 4]);
#pragma unroll
            for (int q = 0; q < 8; q++) {
                float e1 = (q < 4) ? e1a[q] : e1b[q - 4];
                float e2 = (q < 4) ? e2a[q] : e2b[q - 4];
                float p = fmaxf(F1 * e1, F2 * e2);
                p = ((mb >> q) & 1u) ? p : 0.f;
                if (kt == 0) f0[q] = (__bf16)p; else f1[q] = (__bf16)p;
                ps += p;
            }
        }
        lacc += ps;
    };

    stage_tile<FH, THREADS>(hg + (size_t)jt0 * 64, &hbuf[0][0], tid);
    // one-time E table for this block's j range (coalesced s2 reads)
    for (int i = tid; i < NJT * 64; i += THREADS) {
        float s = s2[jt0 * 64 + i];
        el1[i] = EXP2(s);
        el2[i] = EXP2(0.2f * s);
    }
    PLOAD(jt0);
    __syncthreads();                              // el visible (also drains DMA 0)
    bf16x8 fc0, fc1, fn0, fn1;
    PMATH(0, fc0, fc1);                           // tile 0 fragments
    if (NJT > 1) PLOAD(jt0 + 1);

    for (int jl = 0; jl < NJT; jl++) {
        const int b = jl & 1;
        const int jt = jt0 + jl;
        // hbuf[b] DMA drained (vmcnt 0); hbuf[b^1] free to overwrite
        __syncthreads();
        if (jl + 1 < NJT)
            stage_tile<FH, THREADS>(hg + (size_t)(jt + 1) * 64, &hbuf[b ^ 1][0], tid);
        // produce NEXT tile's fragments — interleaves with the MFMA cluster
        if (jl + 1 < NJT) PMATH(jl + 1, fn0, fn1);
        if (jl + 2 < NJT) PLOAD(jt + 2);
        // consume: own m-tile, ALL n-tiles (wave-local, no cross-wave sync)
        __builtin_amdgcn_s_setprio(1);
#pragma unroll
        for (int ntl = 0; ntl < NTL; ntl++) {
            int f = ntl * 16 + rl;
            int s0 = o ^ (rl & 7);                // kt=0 slot
            int s1 = (4 + o) ^ (rl & 7);          // kt=1 slot
            bf16x8 b0 = *(const bf16x8*)(&hbuf[b][(f * 8 + s0) * 8]);
            bf16x8 b1 = *(const bf16x8*)(&hbuf[b][(f * 8 + s1) * 8]);
            acc[ntl] = __builtin_amdgcn_mfma_f32_16x16x32_bf16(fc0, b0, acc[ntl], 0, 0, 0);
            acc[ntl] = __builtin_amdgcn_mfma_f32_16x16x32_bf16(fc1, b1, acc[ntl], 0, 0, 0);
        }
        __builtin_amdgcn_s_setprio(0);
        if (jl + 1 < NJT) { fc0 = fn0; fc1 = fn1; }
    }
    // ---- epilogue: cross-lane lacc reduce (deferred from loop) ----
    lacc += __shfl_xor(lacc, 16, 64);
    lacc += __shfl_xor(lacc, 32, 64);
    if (l < 16) lg[((size_t)head * JSPLIT + js) * NN + row0 + w * 16 + l] = lacc;
#pragma unroll
    for (int ntl = 0; ntl < NTL; ntl++)
#pragma unroll
        for (int r4 = 0; r4 < 4; r4++) {
            int grow = row0 + w * 16 + o * 4 + r4;
            int gcol = head * FH + ntl * 16 + rl;
            accp[((size_t)js * NN + grow) * ldo + gcol] = (__bf16)acc[ntl][r4];
        }
}

// ---------------- combine layer-2 partials + elu + log_softmax -> out ----------------
__global__ void combine2_kernel(const __bf16* __restrict__ accp, const float* __restrict__ lg,
                                float* __restrict__ out) {
    int row = (blockIdx.x * 256 + threadIdx.x) >> 6;
    int lane = threadIdx.x & 63;
    if (row >= NN) return;
    float lsum = 0.f, v = 0.f;
#pragma unroll
    for (int js = 0; js < 16; js++) {
        lsum += lg[(size_t)js * NN + row];
        v += (float)accp[((size_t)js * NN + row) * 64 + lane];
    }
    float inv = lsum > 0.f ? 1.f / lsum : 0.f;
    v *= inv;
    v = v > 0.f ? v : __expf(v) - 1.f;
    float m = v;
#pragma unroll
    for (int off = 1; off < 64; off <<= 1) m = fmaxf(m, __shfl_xor(m, off, 64));
    float ex = __expf(v - m);
    float s = ex;
#pragma unroll
    for (int off = 1; off < 64; off <<= 1) s += __shfl_xor(s, off, 64);
    out[(size_t)row * 64 + lane] = v - m - __logf(s);
}

extern "C" void kernel_launch(void* const* d_in, const int* in_sizes, int n_in,
                              void* d_out, int out_size, void* d_ws, size_t ws_size,
                              hipStream_t stream) {
    const float* X    = (const float*)d_in[0];
    const int*   adj  = (const int*)d_in[1];
    const float* W_h  = (const float*)d_in[2];
    const float* b_h  = (const float*)d_in[3];
    const float* a1_h = (const float*)d_in[4];
    const float* a2_h = (const float*)d_in[5];
    const float* ab_h = (const float*)d_in[6];
    const float* W_o  = (const float*)d_in[7];
    const float* b_o  = (const float*)d_in[8];
    const float* a1_o = (const float*)d_in[9];
    const float* a2_o = (const float*)d_in[10];
    const float* ab_o = (const float*)d_in[11];
    float* out = (float*)d_out;

    // ---- workspace plan with LIFETIME OVERLAYS (R12, proven) ----
    //   * Xb   [prep -> gemm1]   shares its base with accp1 [attn1 -> gemm2]
    //   * accp2 [attn2 -> combine2] aliases accp1's first 8 MB (dead after gemm2)
    //   * lg2   [attn2 -> combine2] aliases accp1+8 MB
    // Footprint: 8.1 MB front + 32 MB overlay = 41.65 MB (= proven R0-R10 size).
    char* ws = (char*)d_ws;
    auto alloc = [&](size_t bytes) {
        char* p = ws; ws += (bytes + 255) & ~(size_t)255; return p;
    };
    unsigned long long* adj_bits = (unsigned long long*)alloc((size_t)NN * 64 * 8); // 2 MB
    __bf16* Bt2    = (__bf16*)alloc((size_t)64 * 512 * 2);      // 64 KB  [prep->gemm2]
    float*  s1h    = (float*)alloc((size_t)4 * NN * 4);         // |-- contiguous,
    float*  s2h    = (float*)alloc((size_t)4 * NN * 4);         // |   zeroed by prep
    float*  s1o    = (float*)alloc((size_t)NN * 4);             // |   (160 KB)
    float*  s2o    = (float*)alloc((size_t)NN * 4);             // |
    float*  lg1    = (float*)alloc((size_t)32 * NN * 4);        // 512 KB [attn1->gemm2]
    __bf16* Ht2    = (__bf16*)alloc((size_t)64 * NN * 2);       // 512 KB [gemm2->attn2]
    float*  biasp  = (float*)alloc(512 * 4);                    // 2 KB
    __bf16* Htg    = (__bf16*)alloc((size_t)512 * NN * 2);      // 4 MB  [gemm1->attn1]
    __bf16* Bt1    = (__bf16*)alloc((size_t)512 * 512 * 2);     // 512 KB [prep->gemm1]
    // ---- overlay region: 32 MB ----
    char*   ovl    = alloc((size_t)8 * NN * 512 * 2);           // 32 MB
    __bf16* Xb     = (__bf16*)ovl;                              // 4 MB  [prep->gemm1]
    __bf16* accp1  = (__bf16*)ovl;                              // 32 MB [attn1->gemm2]
    __bf16* accp2  = (__bf16*)ovl;                              // 8 MB  [attn2->combine2]
    float*  lg2    = (float*)(ovl + (size_t)16 * NN * 64 * 2);  // 256 KB @ +8 MB

    // 1. fused prep: adj->bits, weight prepack, X cast, s1/s2 zeroing
    prep_kernel<<<7168, 256, 0, stream>>>(adj, adj_bits, W_h, b_h, W_o,
                                          Bt1, biasp, Bt2, X, Xb, s1h);
    // 2. layer-1 GEMM fused: Htg (transposed bf16) + s1h/s2h atomics (LOG2E-scaled)
    gemm_fused_kernel<0><<<dim3(8, 64), 256, 0, stream>>>(
        Xb, Bt1, biasp, a1_h, a2_h, Htg, s1h, s2h, nullptr, nullptr, NN, 512, 512);
    // 3. attention layer 1 partials: 128-row/8-wave blocks, 8 j-splits
    //    (32 x 4 x 8 = 1024 blocks x 8 waves; 36 KB LDS -> 4 blocks/CU)
    attn_kernel<128, 8, 8><<<dim3(NN / 128, 4, 8), 512, 0, stream>>>(
        Htg, adj_bits, s1h, s2h, ab_h, accp1, lg1, 512);
    // 4. layer-2 GEMM with combine1 FUSED into the A-path (sums 8 js slices)
    gemm_fused_kernel<1><<<dim3(1, 64), 256, 0, stream>>>(
        nullptr, Bt2, b_o, a1_o, a2_o, Ht2, s1o, s2o, accp1, lg1, NN, 64, 512);
    // 5. attention layer 2 partials (64-row/4-wave, 16 j-splits — unchanged)
    attn_kernel<64, 16, 4><<<dim3(NN / 64, 1, 16), 256, 0, stream>>>(
        Ht2, adj_bits, s1o, s2o, ab_o, accp2, lg2, 64);
    // 6. combine + elu + log_softmax -> out
    combine2_kernel<<<(NN * 64) / 256, 256, 0, stream>>>(accp2, lg2, out);
}

// Round 14
// 197.740 us; speedup vs baseline: 1.6718x; 1.0489x over previous
//
#include <hip/hip_runtime.h>
#include <math.h>

#define NN 4096   // nodes
#define LOG2E 1.44269504088896340736f

using f32x4  = __attribute__((ext_vector_type(4))) float;
using bf16x4 = __attribute__((ext_vector_type(4))) __bf16;
using bf16x8 = __attribute__((ext_vector_type(8))) __bf16;

// exp2 in one v_exp_f32 (inputs are pre-scaled by log2e)
#if __has_builtin(__builtin_amdgcn_exp2f)
#define EXP2(x) __builtin_amdgcn_exp2f(x)
#else
#define EXP2(x) __expf((x) * 0.6931471805599453f)
#endif

// counted-vmcnt barrier (T4): keep next-tile DMA in flight across the barrier.
#define WAITVM4_BARRIER asm volatile("s_waitcnt vmcnt(4)\ns_barrier" ::: "memory")
#define WAITVM0_BARRIER asm volatile("s_waitcnt vmcnt(0)\ns_barrier" ::: "memory")

// ---------------- async global->LDS staging (16B, XOR-swizzled chunks) ----------------
// Row f of 64 bf16 = 8 chunks of 8; LDS slot s of row f holds global chunk s^(f&7).
template<int FH, int THREADS>
__device__ __forceinline__ void stage_tile(const __bf16* __restrict__ hgp,
                                           __bf16* dst, int tid) {
#pragma unroll
    for (int it = 0; it < FH * 64 / 8 / THREADS; it++) {
        int c = tid + it * THREADS;
        int f = c >> 3, sl = c & 7;
        int g = sl ^ (f & 7);
        __builtin_amdgcn_global_load_lds(
            (const __attribute__((address_space(1))) void*)(hgp + (size_t)f * NN + g * 8),
            (__attribute__((address_space(3))) void*)(dst + (size_t)c * 8), 16, 0, 0);
    }
}

__device__ __forceinline__ void stage_g(const __bf16* __restrict__ base, int ldk,
                                        __bf16* dst, int tid) {
#pragma unroll
    for (int it = 0; it < 2; it++) {
        int c = tid + it * 256;
        int f = c >> 3, sl = c & 7;
        int g = sl ^ (f & 7);
        __builtin_amdgcn_global_load_lds(
            (const __attribute__((address_space(1))) void*)(base + (size_t)f * ldk + g * 8),
            (__attribute__((address_space(3))) void*)(dst + (size_t)c * 8), 16, 0, 0);
    }
}

// ---------------- fused prep: memset + prepack + cast + pack_adj ----------------
// pack_adj needs MASSIVE wave parallelism (dependent load->ballot chain):
// 4096 blocks x 4 waves x 16 iters works; 512x4x128 died (R8).
__global__ void prep_kernel(const int* __restrict__ adj, unsigned long long* __restrict__ bits,
                            const float* __restrict__ W_h, const float* __restrict__ b_h,
                            const float* __restrict__ W_o,
                            __bf16* __restrict__ Bt1, float* __restrict__ biasp,
                            __bf16* __restrict__ Bt2,
                            const float* __restrict__ X, __bf16* __restrict__ Xb,
                            float* __restrict__ zeros) {
    const int b = blockIdx.x, t = threadIdx.x;
    if (b < 1024) {                               // prepack + zeroing
        int idx = b * 256 + t;                    // [0, 262144)
        {
            int n = idx >> 9, k = idx & 511;
            int h = n >> 7, f = n & 127;
            Bt1[idx] = (__bf16)W_h[(size_t)h * 512 * 128 + k * 128 + f];
        }
        if (idx < 64 * 512) {
            int n = idx >> 9, k = idx & 511;
            Bt2[idx] = (__bf16)W_o[k * 64 + n];
        }
        if (idx < 512) biasp[idx] = b_h[idx];
        if (idx < (10 * NN) / 4)                  // zero s1h/s2h/s1o/s2o (40960 f32)
            *(f32x4*)(zeros + (size_t)idx * 4) = (f32x4){0.f, 0.f, 0.f, 0.f};
    } else if (b < 3072) {                        // cast X -> bf16
        int i = (b - 1024) * 256 + t;             // [0, 524288) x4 floats
        f32x4 v = *(const f32x4*)(X + (size_t)i * 4);
        bf16x4 o;
#pragma unroll
        for (int q = 0; q < 4; q++) o[q] = (__bf16)v[q];
        *(bf16x4*)(Xb + (size_t)i * 4) = o;
    } else {                                      // pack_adj, grid-strided
        int wave = (b - 3072) * 4 + (t >> 6);     // [0, 16384)
        int lane = t & 63;
        int g0 = wave * 16;                       // 16 consecutive 64-col groups
        for (int it = 0; it < 16; it++) {
            int gw = g0 + it;
            int v = adj[(size_t)gw * 64 + lane];
            unsigned long long m = __ballot(v > 0);
            if (lane == 0) bits[gw] = m;
        }
    }
}

// ---------------- fused bf16 MFMA GEMM ----------------
// FUSEA=0 (layer 1): A staged via global_load_lds, triple-buffer + counted vmcnt.
// FUSEA=1 (layer 2): A = combine1 fused inline (N=64: A read exactly once).
//   Layer-1 attn produces 4 j-split partials (R14 revert), so FUSEA sums 4.
template<int FUSEA>
__global__ __launch_bounds__(256) void gemm_fused_kernel(
    const __bf16* __restrict__ A, const __bf16* __restrict__ Bt,
    const float* __restrict__ bias,
    const float* __restrict__ a1, const float* __restrict__ a2,
    __bf16* __restrict__ Ht, float* __restrict__ s1, float* __restrict__ s2,
    const __bf16* __restrict__ accp, const float* __restrict__ lgin,
    int M, int N, int K)
{
    constexpr int NB = FUSEA ? 2 : 3;
    constexpr int JS1 = 4;                        // layer-1 j-splits (R14: 4)
    __shared__ __attribute__((aligned(16))) __bf16 As[NB][64 * 64];
    __shared__ __attribute__((aligned(16))) __bf16 Bs[NB][64 * 64];
    __shared__ float sinv[4][64];                 // FUSEA: 1/lsum per (head, row)
    const int tid = threadIdx.x, w = tid >> 6, l = tid & 63, o = l >> 4, rl = l & 15;
    const int bm = blockIdx.y * 64, bn = blockIdx.x * 64;
    f32x4 acc[4] = {};
    const int KB = K / 64;

    // FUSEA A-staging: load JS1 js-slices of accp1, combine, elu, bf16,
    // swizzled ds_write (same op order as the old combine1 -> same values).
    auto stageA_fused = [&](int kb, __bf16* dst) {
#pragma unroll
        for (int it = 0; it < 2; it++) {
            int c = tid + it * 256;
            int f = c >> 3, sl = c & 7;
            int row = bm + f;
            int col = kb * 64 + sl * 8;
            float inv = sinv[kb >> 1][f];
            float vs[8] = {0.f, 0.f, 0.f, 0.f, 0.f, 0.f, 0.f, 0.f};
#pragma unroll
            for (int js = 0; js < JS1; js++) {
                bf16x8 t = *(const bf16x8*)(accp + ((size_t)js * NN + row) * 512 + col);
#pragma unroll
                for (int q = 0; q < 8; q++) vs[q] += (float)t[q];
            }
            bf16x8 ob;
#pragma unroll
            for (int q = 0; q < 8; q++) {
                float x = vs[q] * inv;
                x = x > 0.f ? x : __expf(x) - 1.f;
                ob[q] = (__bf16)x;
            }
            *(bf16x8*)(dst + ((size_t)f * 8 + (sl ^ (f & 7))) * 8) = ob;
        }
    };

    if constexpr (FUSEA) {
        {   // per-block inv table: head = tid>>6, row = tid&63
            int h = tid >> 6, r = tid & 63;
            float ls = 0.f;
#pragma unroll
            for (int js = 0; js < JS1; js++)
                ls += lgin[((size_t)(h * JS1 + js)) * NN + bm + r];
            sinv[h][r] = ls > 0.f ? 1.f / ls : 0.f;
        }
        __syncthreads();                          // sinv visible
        stageA_fused(0, &As[0][0]);
        stage_g(Bt + (size_t)bn * K, K, &Bs[0][0], tid);
        for (int kb = 0; kb < KB; kb++) {
            int b = kb & 1;
            __syncthreads();                      // As[b]/Bs[b] ready
            if (kb + 1 < KB) {
                stageA_fused(kb + 1, &As[b ^ 1][0]);
                stage_g(Bt + (size_t)bn * K + (kb + 1) * 64, K, &Bs[b ^ 1][0], tid);
            }
#pragma unroll
            for (int kt = 0; kt < 2; kt++) {
                int ra = w * 16 + rl;
                int cg = kt * 4 + o;
                bf16x8 af = *(const bf16x8*)(&As[b][(ra * 8 + (cg ^ (ra & 7))) * 8]);
#pragma unroll
                for (int nt = 0; nt < 4; nt++) {
                    int rb = nt * 16 + rl;
                    bf16x8 bfr = *(const bf16x8*)(&Bs[b][(rb * 8 + (cg ^ (rb & 7))) * 8]);
                    acc[nt] = __builtin_amdgcn_mfma_f32_16x16x32_bf16(af, bfr, acc[nt], 0, 0, 0);
                }
            }
        }
    } else {
        // prologue: stage tiles 0 and 1 (8 DMA instructions in flight)
        stage_g(A + (size_t)bm * K, K, &As[0][0], tid);
        stage_g(Bt + (size_t)bn * K, K, &Bs[0][0], tid);
        stage_g(A + (size_t)bm * K + 64, K, &As[1][0], tid);
        stage_g(Bt + (size_t)bn * K + 64, K, &Bs[1][0], tid);
        int b = 0;
        for (int kb = 0; kb < KB; kb++) {
            if (kb + 1 < KB) { WAITVM4_BARRIER; } // tile kb landed; kb+1 in flight
            else             { WAITVM0_BARRIER; } // last tile: full drain
#pragma unroll
            for (int kt = 0; kt < 2; kt++) {
                int ra = w * 16 + rl;
                int cg = kt * 4 + o;
                bf16x8 af = *(const bf16x8*)(&As[b][(ra * 8 + (cg ^ (ra & 7))) * 8]);
#pragma unroll
                for (int nt = 0; nt < 4; nt++) {
                    int rb = nt * 16 + rl;
                    bf16x8 bfr = *(const bf16x8*)(&Bs[b][(rb * 8 + (cg ^ (rb & 7))) * 8]);
                    acc[nt] = __builtin_amdgcn_mfma_f32_16x16x32_bf16(af, bfr, acc[nt], 0, 0, 0);
                }
            }
            if (kb + 2 < KB) {                    // stage kb+2 (buffer free by now)
                int b2 = b + 2; if (b2 >= 3) b2 -= 3;
                stage_g(A + (size_t)bm * K + (kb + 2) * 64, K, &As[b2][0], tid);
                stage_g(Bt + (size_t)bn * K + (kb + 2) * 64, K, &Bs[b2][0], tid);
            }
            if (++b == 3) b = 0;
        }
    }
    // epilogue: bias, transposed bf16 store, s1/s2 row-dot partials
    const int head = bn >> 7;
    const int row_base = bm + w * 16 + o * 4;
    float p1[4] = {0.f, 0.f, 0.f, 0.f}, p2[4] = {0.f, 0.f, 0.f, 0.f};
#pragma unroll
    for (int nt = 0; nt < 4; nt++) {
        int col = bn + nt * 16 + rl;
        float bv = bias[col];
        float a1v = a1[col] * LOG2E, a2v = a2[col] * LOG2E;
        bf16x4 hv;
#pragma unroll
        for (int r4 = 0; r4 < 4; r4++) {
            float h = acc[nt][r4] + bv;
            hv[r4] = (__bf16)h;
            p1[r4] += h * a1v;
            p2[r4] += h * a2v;
        }
        *(bf16x4*)(Ht + (size_t)col * M + row_base) = hv;
    }
#pragma unroll
    for (int r4 = 0; r4 < 4; r4++)
#pragma unroll
        for (int off = 1; off < 16; off <<= 1) {
            p1[r4] += __shfl_xor(p1[r4], off, 64);
            p2[r4] += __shfl_xor(p2[r4], off, 64);
        }
    if (rl == 0)
#pragma unroll
        for (int r4 = 0; r4 < 4; r4++) {
            atomicAdd(&s1[(size_t)head * M + row_base + r4], p1[r4]);
            atomicAdd(&s2[(size_t)head * M + row_base + r4], p2[r4]);
        }
}

// ---------------- MFMA attention, SELF-CONSUME + E-factorized softmax ----------------
// R5 structure; R7 PMATH pipelining; R8 setprio placement; R10 E-factorization.
// R14: REVERT to the proven R10 geometry. R13 measured the 8-wave/JSPLIT=8
// variant at equal VGPR budget: attn1 50 µs vs R10's ~40 µs, occupancy flat at
// ~31% — the 2x-TLP-via-wider-blocks hypothesis is falsified (wider barrier
// slack + VGPR squeeze leak beat the DMA-sharing gain). Layer 1: 64-row /
// 4-wave / JSPLIT=4 (LDS 40 KB, exactly 4 blocks/CU). Layer 2: 4-wave /
// JSPLIT=16. __launch_bounds__ 2nd arg = min BLOCKS per CU on this toolchain
// (R12 erratum): (256,4) -> 16 waves/CU, VGPR cap 128, body uses 64, no spill.
template<int FH, int JSPLIT, int NWAVES>
__global__ __launch_bounds__(NWAVES * 64, 4) void attn_kernel(
    const __bf16* __restrict__ Htg,               // [heads*FH][NN]
    const unsigned long long* __restrict__ adj_bits,
    const float* __restrict__ s1_all, const float* __restrict__ s2_all,
    const float* __restrict__ ab_all,
    __bf16* __restrict__ accp,                    // [JSPLIT][NN][ldo]
    float* __restrict__ lg,                       // [heads*JSPLIT][NN]
    int ldo)
{
    constexpr int NJT = NN / 64 / JSPLIT;         // 16 (layer1) / 4 (layer2)
    constexpr int NTL = FH / 16;                  // n-tiles per wave (8 or 4)
    constexpr int THREADS = NWAVES * 64;
    const int head = blockIdx.y;
    const int js   = blockIdx.z;
    const int row0 = blockIdx.x * (NWAVES * 16);
    const int jt0  = js * NJT;
    const int tid = threadIdx.x;
    const int w = tid >> 6, l = tid & 63, o = l >> 4, rl = l & 15;
    const int myrow = row0 + w * 16 + rl;         // this wave's m-tile rows

    __shared__ __attribute__((aligned(16))) __bf16 hbuf[2][FH * 64];
    __shared__ __attribute__((aligned(16))) float el1[NJT * 64];
    __shared__ __attribute__((aligned(16))) float el2[NJT * 64];

    const float* s2 = s2_all + (size_t)head * NN;
    const __bf16* hg = Htg + (size_t)head * FH * NN;
    const float s1r = s1_all[(size_t)head * NN + myrow] + ab_all[head] * LOG2E;
    const float F1 = EXP2(s1r);                   // exp2 of row term
    const float F2 = EXP2(0.2f * s1r);            // exp2 of 0.2*row term
    float lacc = 0.f;                             // per-lane partial; reduced at end
    f32x4 acc[NTL] = {};                          // m-tile w, all n-tiles

    unsigned long long aw;                        // adjacency word (prefetched)
    auto PLOAD = [&](int jt) { aw = adj_bits[(size_t)myrow * 64 + jt]; };
    // PMATH reads E1/E2 from LDS at block-local tile index jl.
    auto PMATH = [&](int jl, bf16x8& f0, bf16x8& f1) {
        float ps = 0.f;
#pragma unroll
        for (int kt = 0; kt < 2; kt++) {
            unsigned int mb = (unsigned int)(aw >> ((kt * 4 + o) * 8)) & 0xFFu;
            int eb = jl * 64 + kt * 32 + o * 8;
            f32x4 e1a = *(const f32x4*)(&el1[eb]);
            f32x4 e1b = *(const f32x4*)(&el1[eb + 4]);
            f32x4 e2a = *(const f32x4*)(&el2[eb]);
            f32x4 e2b = *(const f32x4*)(&el2[eb + 4]);
#pragma unroll
            for (int q = 0; q < 8; q++) {
                float e1 = (q < 4) ? e1a[q] : e1b[q - 4];
                float e2 = (q < 4) ? e2a[q] : e2b[q - 4];
                float p = fmaxf(F1 * e1, F2 * e2);
                p = ((mb >> q) & 1u) ? p : 0.f;
                if (kt == 0) f0[q] = (__bf16)p; else f1[q] = (__bf16)p;
                ps += p;
            }
        }
        lacc += ps;
    };

    stage_tile<FH, THREADS>(hg + (size_t)jt0 * 64, &hbuf[0][0], tid);
    // one-time E table for this block's j range (coalesced s2 reads)
    for (int i = tid; i < NJT * 64; i += THREADS) {
        float s = s2[jt0 * 64 + i];
        el1[i] = EXP2(s);
        el2[i] = EXP2(0.2f * s);
    }
    PLOAD(jt0);
    __syncthreads();                              // el visible (also drains DMA 0)
    bf16x8 fc0, fc1, fn0, fn1;
    PMATH(0, fc0, fc1);                           // tile 0 fragments
    if (NJT > 1) PLOAD(jt0 + 1);

    for (int jl = 0; jl < NJT; jl++) {
        const int b = jl & 1;
        const int jt = jt0 + jl;
        // hbuf[b] DMA drained (vmcnt 0); hbuf[b^1] free to overwrite
        __syncthreads();
        if (jl + 1 < NJT)
            stage_tile<FH, THREADS>(hg + (size_t)(jt + 1) * 64, &hbuf[b ^ 1][0], tid);
        // produce NEXT tile's fragments — interleaves with the MFMA cluster
        if (jl + 1 < NJT) PMATH(jl + 1, fn0, fn1);
        if (jl + 2 < NJT) PLOAD(jt + 2);
        // consume: own m-tile, ALL n-tiles (wave-local, no cross-wave sync)
        __builtin_amdgcn_s_setprio(1);
#pragma unroll
        for (int ntl = 0; ntl < NTL; ntl++) {
            int f = ntl * 16 + rl;
            int s0 = o ^ (rl & 7);                // kt=0 slot
            int s1 = (4 + o) ^ (rl & 7);          // kt=1 slot
            bf16x8 b0 = *(const bf16x8*)(&hbuf[b][(f * 8 + s0) * 8]);
            bf16x8 b1 = *(const bf16x8*)(&hbuf[b][(f * 8 + s1) * 8]);
            acc[ntl] = __builtin_amdgcn_mfma_f32_16x16x32_bf16(fc0, b0, acc[ntl], 0, 0, 0);
            acc[ntl] = __builtin_amdgcn_mfma_f32_16x16x32_bf16(fc1, b1, acc[ntl], 0, 0, 0);
        }
        __builtin_amdgcn_s_setprio(0);
        if (jl + 1 < NJT) { fc0 = fn0; fc1 = fn1; }
    }
    // ---- epilogue: cross-lane lacc reduce (deferred from loop) ----
    lacc += __shfl_xor(lacc, 16, 64);
    lacc += __shfl_xor(lacc, 32, 64);
    if (l < 16) lg[((size_t)head * JSPLIT + js) * NN + row0 + w * 16 + l] = lacc;
#pragma unroll
    for (int ntl = 0; ntl < NTL; ntl++)
#pragma unroll
        for (int r4 = 0; r4 < 4; r4++) {
            int grow = row0 + w * 16 + o * 4 + r4;
            int gcol = head * FH + ntl * 16 + rl;
            accp[((size_t)js * NN + grow) * ldo + gcol] = (__bf16)acc[ntl][r4];
        }
}

// ---------------- combine layer-2 partials + elu + log_softmax -> out ----------------
__global__ void combine2_kernel(const __bf16* __restrict__ accp, const float* __restrict__ lg,
                                float* __restrict__ out) {
    int row = (blockIdx.x * 256 + threadIdx.x) >> 6;
    int lane = threadIdx.x & 63;
    if (row >= NN) return;
    float lsum = 0.f, v = 0.f;
#pragma unroll
    for (int js = 0; js < 16; js++) {
        lsum += lg[(size_t)js * NN + row];
        v += (float)accp[((size_t)js * NN + row) * 64 + lane];
    }
    float inv = lsum > 0.f ? 1.f / lsum : 0.f;
    v *= inv;
    v = v > 0.f ? v : __expf(v) - 1.f;
    float m = v;
#pragma unroll
    for (int off = 1; off < 64; off <<= 1) m = fmaxf(m, __shfl_xor(m, off, 64));
    float ex = __expf(v - m);
    float s = ex;
#pragma unroll
    for (int off = 1; off < 64; off <<= 1) s += __shfl_xor(s, off, 64);
    out[(size_t)row * 64 + lane] = v - m - __logf(s);
}

extern "C" void kernel_launch(void* const* d_in, const int* in_sizes, int n_in,
                              void* d_out, int out_size, void* d_ws, size_t ws_size,
                              hipStream_t stream) {
    const float* X    = (const float*)d_in[0];
    const int*   adj  = (const int*)d_in[1];
    const float* W_h  = (const float*)d_in[2];
    const float* b_h  = (const float*)d_in[3];
    const float* a1_h = (const float*)d_in[4];
    const float* a2_h = (const float*)d_in[5];
    const float* ab_h = (const float*)d_in[6];
    const float* W_o  = (const float*)d_in[7];
    const float* b_o  = (const float*)d_in[8];
    const float* a1_o = (const float*)d_in[9];
    const float* a2_o = (const float*)d_in[10];
    const float* ab_o = (const float*)d_in[11];
    float* out = (float*)d_out;

    // R10-proven linear workspace (~36 MB).
    char* ws = (char*)d_ws;
    auto alloc = [&](size_t bytes) {
        char* p = ws; ws += (bytes + 255) & ~(size_t)255; return p;
    };
    unsigned long long* adj_bits = (unsigned long long*)alloc((size_t)NN * 64 * 8); // 2 MB
    __bf16* Bt1    = (__bf16*)alloc((size_t)512 * 512 * 2);     // 512 KB
    float*  biasp  = (float*)alloc(512 * 4);
    __bf16* Bt2    = (__bf16*)alloc((size_t)64 * 512 * 2);      // 64 KB
    __bf16* Xb     = (__bf16*)alloc((size_t)NN * 512 * 2);      // 4 MB
    float*  s1h    = (float*)alloc((size_t)4 * NN * 4);         // |-- contiguous,
    float*  s2h    = (float*)alloc((size_t)4 * NN * 4);         // |   zeroed by prep
    float*  s1o    = (float*)alloc((size_t)NN * 4);             // |   (160 KB)
    float*  s2o    = (float*)alloc((size_t)NN * 4);             // |
    __bf16* Htg    = (__bf16*)alloc((size_t)512 * NN * 2);      // 4 MB
    __bf16* accp1  = (__bf16*)alloc((size_t)4 * NN * 512 * 2);  // 16 MB
    float*  lg1    = (float*)alloc((size_t)16 * NN * 4);        // 256 KB
    __bf16* Ht2    = (__bf16*)alloc((size_t)64 * NN * 2);       // 512 KB
    __bf16* accp2  = (__bf16*)alloc((size_t)16 * NN * 64 * 2);  // 8 MB
    float*  lg2    = (float*)alloc((size_t)16 * NN * 4);        // 256 KB  (~36 MB)

    // 1. fused prep: adj->bits, weight prepack, X cast, s1/s2 zeroing
    prep_kernel<<<7168, 256, 0, stream>>>(adj, adj_bits, W_h, b_h, W_o,
                                          Bt1, biasp, Bt2, X, Xb, s1h);
    // 2. layer-1 GEMM fused: Htg (transposed bf16) + s1h/s2h atomics (LOG2E-scaled)
    gemm_fused_kernel<0><<<dim3(8, 64), 256, 0, stream>>>(
        Xb, Bt1, biasp, a1_h, a2_h, Htg, s1h, s2h, nullptr, nullptr, NN, 512, 512);
    // 3. attention layer 1 partials (4 heads x 4 j-splits, 64-row/4-wave blocks)
    attn_kernel<128, 4, 4><<<dim3(NN / 64, 4, 4), 256, 0, stream>>>(
        Htg, adj_bits, s1h, s2h, ab_h, accp1, lg1, 512);
    // 4. layer-2 GEMM with combine1 FUSED into the A-path (sums 4 js slices)
    gemm_fused_kernel<1><<<dim3(1, 64), 256, 0, stream>>>(
        nullptr, Bt2, b_o, a1_o, a2_o, Ht2, s1o, s2o, accp1, lg1, NN, 64, 512);
    // 5. attention layer 2 partials (64-row/4-wave, 16 j-splits)
    attn_kernel<64, 16, 4><<<dim3(NN / 64, 1, 16), 256, 0, stream>>>(
        Ht2, adj_bits, s1o, s2o, ab_o, accp2, lg2, 64);
    // 6. combine + elu + log_softmax -> out
    combine2_kernel<<<(NN * 64) / 256, 256, 0, stream>>>(accp2, lg2, out);
}